// Round 16
// baseline (785.163 us; speedup 1.0000x reference)
//
#include <hip/hip_runtime.h>
#include <hip/hip_bf16.h>
#include <math.h>

#define Bsz 512
#define Hd 1024
#define Vd 512
#define Cc 128
#define Ll 120
#define Kk 10
#define Oo 32
#define NSTEP 30

typedef __attribute__((ext_vector_type(8))) short bf16x8;
typedef __attribute__((ext_vector_type(4))) float f32x4;
typedef unsigned short ushort;
typedef unsigned long long u64;

// raw barrier: drain LDS ops only; global loads stay in flight (counted vmcnt at use)
#define BARLDS() asm volatile("s_waitcnt lgkmcnt(0)\n\ts_barrier" ::: "memory")

static __device__ __forceinline__ float sigm(float x) { return 1.f / (1.f + expf(-x)); }
static __device__ __forceinline__ ushort f2bf(float x) {
    __hip_bfloat16 h = __float2bfloat16(x);
    return *(ushort*)&h;
}
static __device__ __forceinline__ float bf2f(ushort u) {
    __hip_bfloat16 h; *(ushort*)&h = u;
    return __bfloat162float(h);
}
static __device__ __forceinline__ unsigned monofy(float f) {
    unsigned u = __float_as_uint(f);
    return (u & 0x80000000u) ? ~u : (u | 0x80000000u);
}

// ---------- merged pack: wih | whh | wout | emb in one launch ----------
__global__ void k_packall(const float* __restrict__ wih, ushort* __restrict__ wihH, ushort* __restrict__ wihL,
                          const float* __restrict__ whh, ushort* __restrict__ whhH, ushort* __restrict__ whhL,
                          const float* __restrict__ wout, ushort* __restrict__ woutH, ushort* __restrict__ woutL,
                          const float* __restrict__ emb, ushort* __restrict__ embH, ushort* __restrict__ embL) {
    int gidx = blockIdx.x * 256 + threadIdx.x;
    const float* W;
    ushort *hi, *lo;
    int idx;
    if (gidx < 3145728)      { W = wih;  hi = wihH;  lo = wihL;  idx = gidx; }
    else if (gidx < 6291456) { W = whh;  hi = whhH;  lo = whhL;  idx = gidx - 3145728; }
    else if (gidx < 6815744) { W = wout; hi = woutH; lo = woutL; idx = gidx - 6291456; }
    else if (gidx < 7340032) { W = emb;  hi = embH;  lo = embL;  idx = gidx - 6815744; }
    else return;
    int jj = idx & 7, l = (idx >> 3) & 63, c = (idx >> 9) & 31, nf = idx >> 14;
    int n = nf * 16 + (l & 15);
    int k = c * 32 + ((l >> 4) << 3) + jj;
    float v = W[(size_t)n * 1024 + k];
    ushort h = f2bf(v);
    hi[idx] = h;
    lo[idx] = f2bf(v - bf2f(h));
}

// ---------- pack conv_w [O,C,K] into B-frag layout over K'=(kconv,c)=1280 ----------
__global__ void k_packconv(const float* __restrict__ cw, ushort* __restrict__ hi,
                           ushort* __restrict__ lo) {
    int idx = blockIdx.x * 256 + threadIdx.x;
    if (idx >= 2 * 40 * 64 * 8) return;
    int jj = idx & 7, l = (idx >> 3) & 63, ch = (idx >> 9) % 40, nf = idx / (40 * 512);
    int o = nf * 16 + (l & 15);
    int k = ch * 32 + ((l >> 4) << 3) + jj;
    int kc = k >> 7, c = k & 127;
    float v = cw[(o * Cc + c) * Kk + kc];
    ushort h = f2bf(v);
    hi[idx] = h;
    lo[idx] = f2bf(v - bf2f(h));
}

// ---------- conv v3: dual-slab blocks (round-12/14 measured good) ----------
__global__ __launch_bounds__(512) void k_convmfma(const float* __restrict__ sm,
                                                  const ushort* __restrict__ wH,
                                                  const ushort* __restrict__ wL,
                                                  const float* __restrict__ cb,
                                                  const float* __restrict__ ew,
                                                  const float* __restrict__ eb,
                                                  float* __restrict__ h0,
                                                  ushort* __restrict__ ApHi,
                                                  ushort* __restrict__ ApLo) {
    __shared__ ushort hiS[2][137 * 128];
    __shared__ ushort loS[2][137 * 128];
    __shared__ float sred[8][2][2][16];
    __shared__ float ps[2][Oo];
    int b0 = blockIdx.x * 2, tid = threadIdx.x, wid = tid >> 6, l = tid & 63;

    for (int i = tid; i < 3840; i += 512) {
        int s = i >= 1920;
        int local = i - s * 1920;
        int row = local >> 4, col0 = (local & 15) * 8;
        const float* smb = sm + (size_t)(b0 + s) * (Ll * Cc);
        float4 fa = *(const float4*)(smb + row * Cc + col0);
        float4 fb = *(const float4*)(smb + row * Cc + col0 + 4);
        float vv[8] = {fa.x, fa.y, fa.z, fa.w, fb.x, fb.y, fb.z, fb.w};
        ushort h8[8], l8[8];
#pragma unroll
        for (int q = 0; q < 8; ++q) {
            ushort h = f2bf(vv[q]);
            h8[q] = h;
            l8[q] = f2bf(vv[q] - bf2f(h));
        }
        int o = ((row << 8) + (col0 << 1)) ^ ((row & 7) << 4);
        *(bf16x8*)((char*)hiS[s] + o) = *(bf16x8*)h8;
        *(bf16x8*)((char*)loS[s] + o) = *(bf16x8*)l8;
    }
    __syncthreads();

    f32x4 acc[2][2];
#pragma unroll
    for (int s = 0; s < 2; ++s)
#pragma unroll
        for (int j = 0; j < 2; ++j) acc[s][j] = (f32x4)0.f;

    bf16x8 aH0[2], aL0[2], bH0[2], bL0[2];
    bf16x8 aH1[2], aL1[2], bH1[2], bL1[2];

#define CLD(AH, AL, BH, BL, ch)                                                        \
    {                                                                                  \
        int row = wid * 16 + (l & 15) + ((ch) >> 2);                                   \
        int o = ((row << 8) + ((((ch) & 3) * 32 + ((l >> 4) << 3)) << 1))              \
                ^ ((row & 7) << 4);                                                    \
        _Pragma("unroll") for (int s = 0; s < 2; ++s) {                                \
            AH[s] = *(const bf16x8*)((const char*)hiS[s] + o);                         \
            AL[s] = *(const bf16x8*)((const char*)loS[s] + o);                         \
        }                                                                              \
        _Pragma("unroll") for (int nf = 0; nf < 2; ++nf) {                             \
            int boff = ((nf * 40 + (ch)) * 64 + l) * 8;                                \
            BH[nf] = *(const bf16x8*)(wH + boff);                                      \
            BL[nf] = *(const bf16x8*)(wL + boff);                                      \
        }                                                                              \
    }
#define CST(AH, AL, BH, BL)                                                            \
    {                                                                                  \
        _Pragma("unroll") for (int s = 0; s < 2; ++s)                                  \
            _Pragma("unroll") for (int nf = 0; nf < 2; ++nf) {                         \
                acc[s][nf] = __builtin_amdgcn_mfma_f32_16x16x32_bf16(AH[s], BH[nf], acc[s][nf], 0, 0, 0); \
                acc[s][nf] = __builtin_amdgcn_mfma_f32_16x16x32_bf16(AH[s], BL[nf], acc[s][nf], 0, 0, 0); \
                acc[s][nf] = __builtin_amdgcn_mfma_f32_16x16x32_bf16(AL[s], BH[nf], acc[s][nf], 0, 0, 0); \
            }                                                                          \
    }

    CLD(aH0, aL0, bH0, bL0, 0)
#pragma unroll
    for (int ch = 0; ch < 40; ch += 2) {
        CLD(aH1, aL1, bH1, bL1, ch + 1)
        CST(aH0, aL0, bH0, bL0)
        if (ch + 2 < 40) CLD(aH0, aL0, bH0, bL0, ch + 2)
        CST(aH1, aL1, bH1, bL1)
    }
#undef CLD
#undef CST

    float mx[2][2] = {{-1e38f, -1e38f}, {-1e38f, -1e38f}};
    {
        int tb = wid * 16 + ((l >> 4) << 2);
#pragma unroll
        for (int q = 0; q < 4; ++q) {
            if (tb + q <= 110) {
#pragma unroll
                for (int s = 0; s < 2; ++s) {
                    mx[s][0] = fmaxf(mx[s][0], acc[s][0][q]);
                    mx[s][1] = fmaxf(mx[s][1], acc[s][1][q]);
                }
            }
        }
    }
#pragma unroll
    for (int sh = 16; sh < 64; sh <<= 1) {
#pragma unroll
        for (int s = 0; s < 2; ++s) {
            mx[s][0] = fmaxf(mx[s][0], __shfl_xor(mx[s][0], sh));
            mx[s][1] = fmaxf(mx[s][1], __shfl_xor(mx[s][1], sh));
        }
    }
    if (l < 16) {
#pragma unroll
        for (int s = 0; s < 2; ++s) {
            sred[wid][s][0][l] = mx[s][0];
            sred[wid][s][1][l] = mx[s][1];
        }
    }
    __syncthreads();
    if (tid < 64) {
        int s = tid >> 5, o = tid & 31;
        float m = sred[0][s][o >> 4][o & 15];
#pragma unroll
        for (int w = 1; w < 8; ++w) m = fmaxf(m, sred[w][s][o >> 4][o & 15]);
        ps[s][o] = fmaxf(m + cb[o], 0.f);
    }
    __syncthreads();
    for (int j = tid; j < Hd; j += 512) {
        const float4* e4 = (const float4*)(ew + (size_t)j * Oo);
        float4 w0 = e4[0], w1 = e4[1], w2 = e4[2], w3 = e4[3];
        float4 w4 = e4[4], w5 = e4[5], w6 = e4[6], w7 = e4[7];
        float ebj = eb[j];
        int c = j >> 5, sub = (j >> 3) & 3, jj = j & 7;
#pragma unroll
        for (int s = 0; s < 2; ++s) {
            int b = b0 + s;
            const float* p = ps[s];
            float a = ebj;
            a += p[0] * w0.x + p[1] * w0.y + p[2] * w0.z + p[3] * w0.w;
            a += p[4] * w1.x + p[5] * w1.y + p[6] * w1.z + p[7] * w1.w;
            a += p[8] * w2.x + p[9] * w2.y + p[10] * w2.z + p[11] * w2.w;
            a += p[12] * w3.x + p[13] * w3.y + p[14] * w3.z + p[15] * w3.w;
            a += p[16] * w4.x + p[17] * w4.y + p[18] * w4.z + p[19] * w4.w;
            a += p[20] * w5.x + p[21] * w5.y + p[22] * w5.z + p[23] * w5.w;
            a += p[24] * w6.x + p[25] * w6.y + p[26] * w6.z + p[27] * w6.w;
            a += p[28] * w7.x + p[29] * w7.y + p[30] * w7.z + p[31] * w7.w;
            a = fmaxf(a, 0.f);
            h0[(size_t)b * Hd + j] = a;
            ushort hb = f2bf(a);
            ushort lb = f2bf(a - bf2f(hb));
            int amf = b >> 4;
            int lane_r = (b & 15) + (sub << 4);
            int flat = ((amf * 32 + c) * 64 + lane_r) * 8 + jj;
            ApHi[flat] = hb;
            ApLo[flat] = lb;
        }
    }
}

// ---------- gi table (setup): r6-verified 8-wave GEMM, plain store epilogue ----------
__global__ __launch_bounds__(512, 2) void k_gi(const ushort* __restrict__ Ah,
                                               const ushort* __restrict__ Al,
                                               const ushort* __restrict__ Bh,
                                               const ushort* __restrict__ Bl,
                                               const float* __restrict__ bias,
                                               float* __restrict__ outF) {
    __shared__ ushort Bs[2][48][512];
    int id = blockIdx.x;
    int xcd = id & 7, r = id >> 3;
    int jt = xcd * 4 + (r & 3);
    int mt = r >> 2;
    int tid = threadIdx.x, wid = tid >> 6, l = tid & 63;
    int wm = wid >> 1, wj = wid & 1;
    int mf = mt * 4 + wm;
    int jf = jt * 2 + wj;
    int jcol = jf * 16 + (l & 15);

    f32x4 acc[3];
#pragma unroll
    for (int g = 0; g < 3; ++g) acc[g] = (f32x4)0.f;

    bf16x8 stg[6], aH0[4], aL0[4], aH1[4], aL1[4];

#define STG_LD(it)                                                                     \
    {                                                                                  \
        _Pragma("unroll") for (int k = 0; k < 6; ++k) {                                \
            int u = wid + 8 * k;                                                       \
            int hl = u & 1, wjb = (u >> 1) & 1, g = (u >> 2) % 3, cu = u / 12;         \
            const ushort* sp = hl ? Bl : Bh;                                           \
            stg[k] = *(const bf16x8*)(sp +                                             \
                (size_t)(((g * 64 + jt * 2 + wjb) * 32 + (it) * 4 + cu) * 64 + l) * 8);\
        }                                                                              \
    }
#define STG_WR(buf)                                                                    \
    {                                                                                  \
        _Pragma("unroll") for (int k = 0; k < 6; ++k)                                  \
            *(bf16x8*)&Bs[buf][wid + 8 * k][l * 8] = stg[k];                           \
    }
#define A_LD(DH, DL, it)                                                               \
    {                                                                                  \
        _Pragma("unroll") for (int cc = 0; cc < 4; ++cc) {                             \
            DH[cc] = *(const bf16x8*)(Ah + (size_t)((mf * 32 + (it) * 4 + cc) * 64 + l) * 8); \
            DL[cc] = *(const bf16x8*)(Al + (size_t)((mf * 32 + (it) * 4 + cc) * 64 + l) * 8); \
        }                                                                              \
    }
#define CMP(buf, AH, AL)                                                               \
    {                                                                                  \
        _Pragma("unroll") for (int cc = 0; cc < 4; ++cc)                               \
            _Pragma("unroll") for (int g = 0; g < 3; ++g) {                            \
                bf16x8 bhh = *(const bf16x8*)&Bs[buf][cc * 12 + g * 4 + wj * 2 + 0][l * 8]; \
                bf16x8 bll = *(const bf16x8*)&Bs[buf][cc * 12 + g * 4 + wj * 2 + 1][l * 8]; \
                acc[g] = __builtin_amdgcn_mfma_f32_16x16x32_bf16(AH[cc], bhh, acc[g], 0, 0, 0); \
                acc[g] = __builtin_amdgcn_mfma_f32_16x16x32_bf16(AH[cc], bll, acc[g], 0, 0, 0); \
                acc[g] = __builtin_amdgcn_mfma_f32_16x16x32_bf16(AL[cc], bhh, acc[g], 0, 0, 0); \
            }                                                                          \
    }

    STG_LD(0)
    STG_WR(0)
    STG_LD(1)
    A_LD(aH0, aL0, 0)
    BARLDS();
#pragma unroll
    for (int it = 0; it < 8; ++it) {
        int buf = it & 1;
        if (it < 7) STG_WR(buf ^ 1)
        if (it < 6) STG_LD(it + 2)
        if (it & 1) {
            if (it < 7) A_LD(aH0, aL0, it + 1)
            CMP(buf, aH1, aL1)
        } else {
            if (it < 7) A_LD(aH1, aL1, it + 1)
            CMP(buf, aH0, aL0)
        }
        BARLDS();
    }
#undef STG_LD
#undef STG_WR
#undef A_LD
#undef CMP

#pragma unroll
    for (int q = 0; q < 4; ++q) {
        int b = mf * 16 + ((l >> 4) << 2) + q;
#pragma unroll
        for (int g = 0; g < 3; ++g)
            outF[(size_t)b * 3072 + g * 1024 + jcol] = acc[g][q] + bias[g * 1024 + jcol];
    }
}

// ---------- recurrent GEMM v5: 512 blocks x 4 waves, K=128/it (8 its), 48 KB dbuf ----------
// grid 512 = 8 mt x 64 jf (jf XCD-pinned); M=64 rows (1 mf/wave) x 16 j x 3 gates.
// Combines r14's 8-barrier depth with r15's multi-block co-residency (3 blocks/CU by LDS).
__global__ __launch_bounds__(256, 2) void k_rnnS(const ushort* __restrict__ Ah,
                                                 const ushort* __restrict__ Al,
                                                 const ushort* __restrict__ Bh,
                                                 const ushort* __restrict__ Bl,
                                                 const float* __restrict__ bias,
                                                 float* __restrict__ outF,
                                                 const float* __restrict__ gi_all,
                                                 const u64* __restrict__ pkRd,
                                                 u64* __restrict__ pkWr,
                                                 float* __restrict__ outIdxRow,
                                                 const float* __restrict__ hOld,
                                                 ushort* __restrict__ ApHi,
                                                 ushort* __restrict__ ApLo) {
    __shared__ ushort Bs[2][24][512];   // 48 KB dbuf (K=128 slice)
    int id = blockIdx.x;
    int xcd = id & 7, r = id >> 3;      // r 0..63
    int jf = xcd * 8 + (r & 7);         // 0..63 (8 jf per XCD -> panel L2-resident)
    int mt = r >> 3;                    // 0..7
    int tid = threadIdx.x, wm = tid >> 6, l = tid & 63;
    int mf = mt * 4 + wm;               // 0..31
    int jcol = jf * 16 + (l & 15);

    f32x4 acc[3];
#pragma unroll
    for (int g = 0; g < 3; ++g) acc[g] = (f32x4)0.f;

    bf16x8 stg[6], aH0[4], aL0[4], aH1[4], aL1[4];

#define SSTG_LD(it)                                                                    \
    {                                                                                  \
        _Pragma("unroll") for (int k = 0; k < 6; ++k) {                                \
            int s = tid + 256 * k;                                                     \
            int il = s & 63, u = s >> 6;                                               \
            int hl = u & 1, g = (u >> 1) % 3, cu = u / 6;                              \
            const ushort* sp = hl ? Bl : Bh;                                           \
            stg[k] = *(const bf16x8*)(sp +                                             \
                (size_t)(((g * 64 + jf) * 32 + (it) * 4 + cu) * 64 + il) * 8);         \
        }                                                                              \
    }
#define SSTG_WR(buf)                                                                   \
    {                                                                                  \
        _Pragma("unroll") for (int k = 0; k < 6; ++k) {                                \
            int s = tid + 256 * k;                                                     \
            int il = s & 63, u = s >> 6;                                               \
            *(bf16x8*)&Bs[buf][u][il * 8] = stg[k];                                    \
        }                                                                              \
    }
#define SA_LD(DH, DL, it)                                                              \
    {                                                                                  \
        _Pragma("unroll") for (int cc = 0; cc < 4; ++cc) {                             \
            size_t off = (size_t)((mf * 32 + (it) * 4 + cc) * 64 + l) * 8;             \
            DH[cc] = *(const bf16x8*)(Ah + off);                                       \
            DL[cc] = *(const bf16x8*)(Al + off);                                       \
        }                                                                              \
    }
#define SCMP(buf, AH, AL)                                                              \
    {                                                                                  \
        _Pragma("unroll") for (int cc = 0; cc < 4; ++cc)                               \
            _Pragma("unroll") for (int g = 0; g < 3; ++g) {                            \
                bf16x8 bhh = *(const bf16x8*)&Bs[buf][cc * 6 + g * 2 + 0][l * 8];      \
                bf16x8 bll = *(const bf16x8*)&Bs[buf][cc * 6 + g * 2 + 1][l * 8];      \
                acc[g] = __builtin_amdgcn_mfma_f32_16x16x32_bf16(AH[cc], bhh, acc[g], 0, 0, 0); \
                acc[g] = __builtin_amdgcn_mfma_f32_16x16x32_bf16(AH[cc], bll, acc[g], 0, 0, 0); \
                acc[g] = __builtin_amdgcn_mfma_f32_16x16x32_bf16(AL[cc], bhh, acc[g], 0, 0, 0); \
            }                                                                          \
    }

    SSTG_LD(0)
    SSTG_WR(0)
    SSTG_LD(1)
    SA_LD(aH0, aL0, 0)

    // epilogue operand gather issued early (overlaps the K-loop)
    float giR[4][3], hR[4];
    int bR[4], tkR[4];
#pragma unroll
    for (int q = 0; q < 4; ++q) {
        bR[q] = mf * 16 + ((l >> 4) << 2) + q;
        u64 pk = pkRd[bR[q]];
        tkR[q] = 511 - (int)(unsigned)(pk & 0xFFFFFFFFu);
        const float* gi = gi_all + (size_t)tkR[q] * 3072;
        giR[q][0] = gi[jcol];
        giR[q][1] = gi[1024 + jcol];
        giR[q][2] = gi[2048 + jcol];
        hR[q] = hOld[(size_t)bR[q] * 1024 + jcol];
    }
    if (jf == 0 && (l & 15) == 0) {
#pragma unroll
        for (int q = 0; q < 4; ++q) {
            pkWr[bR[q]] = 0ULL;
            if (outIdxRow) outIdxRow[bR[q]] = (float)tkR[q];
        }
    }

    BARLDS();
#pragma unroll
    for (int it = 0; it < 8; ++it) {
        int buf = it & 1;
        if (it < 7) SSTG_WR(buf ^ 1)
        if (it < 6) SSTG_LD(it + 2)
        if (it & 1) {
            if (it < 7) SA_LD(aH0, aL0, it + 1)
            SCMP(buf, aH1, aL1)
        } else {
            if (it < 7) SA_LD(aH1, aL1, it + 1)
            SCMP(buf, aH0, aL0)
        }
        BARLDS();
    }
#undef SSTG_LD
#undef SSTG_WR
#undef SA_LD
#undef SCMP

    {
        float bj0 = bias[jcol], bj1 = bias[1024 + jcol], bj2 = bias[2048 + jcol];
        int c = jcol >> 5, sub = (jcol >> 3) & 3, jj = jcol & 7;
#pragma unroll
        for (int q = 0; q < 4; ++q) {
            int b = bR[q];
            float rr = sigm(giR[q][0] + acc[0][q] + bj0);
            float zz = sigm(giR[q][1] + acc[1][q] + bj1);
            float nn = tanhf(giR[q][2] + rr * (acc[2][q] + bj2));
            float hv = (1.f - zz) * nn + zz * hR[q];
            outF[(size_t)b * 1024 + jcol] = hv;
            ushort hb = f2bf(hv);
            ushort lb = f2bf(hv - bf2f(hb));
            int lane_r = (b & 15) + (sub << 4);
            int flat = (((b >> 4) * 32 + c) * 64 + lane_r) * 8 + jj;
            ApHi[flat] = hb;
            ApLo[flat] = lb;
        }
    }
}

// ---------- logits GEMM: B vf-panel LDS-staged + A register prefetch + fused argmax ----------
__global__ __launch_bounds__(256) void k_lgt(const ushort* __restrict__ Ah,
                                             const ushort* __restrict__ Al,
                                             const ushort* __restrict__ Bh,
                                             const ushort* __restrict__ Bl,
                                             const float* __restrict__ bias,
                                             float* __restrict__ outF,
                                             u64* __restrict__ pkOut) {
    __shared__ ushort Bs[2][8][512];    // 16 KB
    int id = blockIdx.x;
    int xcd = id & 7, r = id >> 3;
    int vf = xcd * 4 + (r & 3);
    int mg = r >> 2;
    int tid = threadIdx.x, w = tid >> 6, l = tid & 63;
    int mf = mg * 4 + w;

    f32x4 acc = (f32x4)0.f;
    bf16x8 stg[2];
    bf16x8 a0h[4], a0l[4], a1h[4], a1l[4];

#define LSTG_LD(it)                                                                    \
    {                                                                                  \
        _Pragma("unroll") for (int k = 0; k < 2; ++k) {                                \
            int s = tid + 256 * k;                                                     \
            int il = s & 63, u = s >> 6;                                               \
            int hl = u & 1, cu = u >> 1;                                               \
            const ushort* sp = hl ? Bl : Bh;                                           \
            stg[k] = *(const bf16x8*)(sp +                                             \
                (size_t)((vf * 32 + (it) * 4 + cu) * 64 + il) * 8);                    \
        }                                                                              \
    }
#define LSTG_WR(buf)                                                                   \
    {                                                                                  \
        _Pragma("unroll") for (int k = 0; k < 2; ++k) {                                \
            int s = tid + 256 * k;                                                     \
            int il = s & 63, u = s >> 6;                                               \
            *(bf16x8*)&Bs[buf][u][il * 8] = stg[k];                                    \
        }                                                                              \
    }
#define LA_LD(DH, DL, it)                                                              \
    {                                                                                  \
        _Pragma("unroll") for (int cu = 0; cu < 4; ++cu) {                             \
            size_t aoff = (size_t)((mf * 32 + (it) * 4 + cu) * 64 + l) * 8;            \
            DH[cu] = *(const bf16x8*)(Ah + aoff);                                      \
            DL[cu] = *(const bf16x8*)(Al + aoff);                                      \
        }                                                                              \
    }
#define LCMP(buf, AH, AL)                                                              \
    {                                                                                  \
        _Pragma("unroll") for (int cu = 0; cu < 4; ++cu) {                             \
            bf16x8 bh = *(const bf16x8*)&Bs[buf][cu * 2 + 0][l * 8];                   \
            bf16x8 bl = *(const bf16x8*)&Bs[buf][cu * 2 + 1][l * 8];                   \
            acc = __builtin_amdgcn_mfma_f32_16x16x32_bf16(AH[cu], bh, acc, 0, 0, 0);   \
            acc = __builtin_amdgcn_mfma_f32_16x16x32_bf16(AH[cu], bl, acc, 0, 0, 0);   \
            acc = __builtin_amdgcn_mfma_f32_16x16x32_bf16(AL[cu], bh, acc, 0, 0, 0);   \
        }                                                                              \
    }

    LSTG_LD(0)
    LSTG_WR(0)
    LSTG_LD(1)
    LA_LD(a0h, a0l, 0)
    BARLDS();
#pragma unroll
    for (int it = 0; it < 8; ++it) {
        int buf = it & 1;
        if (it < 7) LSTG_WR(buf ^ 1)
        if (it < 6) LSTG_LD(it + 2)
        if (it & 1) {
            if (it < 7) LA_LD(a0h, a0l, it + 1)
            LCMP(buf, a1h, a1l)
        } else {
            if (it < 7) LA_LD(a1h, a1l, it + 1)
            LCMP(buf, a0h, a0l)
        }
        BARLDS();
    }
#undef LSTG_LD
#undef LSTG_WR
#undef LA_LD
#undef LCMP

    int v = vf * 16 + (l & 15);
    float bv = bias[v];
    float lg[4];
    unsigned vmq[4];
#pragma unroll
    for (int q = 0; q < 4; ++q) {
        int b = mf * 16 + ((l >> 4) << 2) + q;
        lg[q] = acc[q] + bv;
        if (outF) outF[(size_t)b * Vd + v] = lg[q];
        vmq[q] = 511u - (unsigned)v;
    }
#pragma unroll
    for (int off = 1; off < 16; off <<= 1) {
#pragma unroll
        for (int q = 0; q < 4; ++q) {
            float og = __shfl_xor(lg[q], off);
            unsigned ov = __shfl_xor(vmq[q], off);
            if (og > lg[q] || (og == lg[q] && ov > vmq[q])) { lg[q] = og; vmq[q] = ov; }
        }
    }
    if ((l & 15) == 0) {
#pragma unroll
        for (int q = 0; q < 4; ++q) {
            int b = mf * 16 + ((l >> 4) << 2) + q;
            u64 pk = ((u64)monofy(lg[q]) << 32) | (u64)vmq[q];
            atomicMax(&pkOut[b], pk);
        }
    }
}

// ---------- final: log_softmax of last logits + decoded_indices row 30 ----------
__global__ __launch_bounds__(64) void k_fin(const float* __restrict__ logits,
                                            const u64* __restrict__ pk,
                                            float* __restrict__ out_lsm,
                                            float* __restrict__ outIdxRow) {
    int b = blockIdx.x, l = threadIdx.x;
    const float* row = logits + (size_t)b * Vd;
    float bv = -3.4e38f;
#pragma unroll
    for (int s = 0; s < 8; ++s) bv = fmaxf(bv, row[s * 64 + l]);
#pragma unroll
    for (int off = 1; off < 64; off <<= 1) bv = fmaxf(bv, __shfl_xor(bv, off));
    float sum = 0.f;
#pragma unroll
    for (int s = 0; s < 8; ++s) sum += expf(row[s * 64 + l] - bv);
#pragma unroll
    for (int off = 1; off < 64; off <<= 1) sum += __shfl_xor(sum, off);
    float lse = logf(sum) + bv;
#pragma unroll
    for (int s = 0; s < 8; ++s) {
        int v = s * 64 + l;
        out_lsm[(size_t)b * Vd + v] = row[v] - lse;
    }
    if (l == 0)
        outIdxRow[b] = (float)(511 - (int)(unsigned)(pk[b] & 0xFFFFFFFFu));
}

__global__ void k_init(u64* __restrict__ P0, float* __restrict__ out_idx0) {
    int i = blockIdx.x * 64 + threadIdx.x;
    if (i < Bsz) {
        P0[i] = (1ULL << 32) | 511ULL;   // decodes to token 0 (SOS)
        out_idx0[i] = 0.f;
    }
}

extern "C" void kernel_launch(void* const* d_in, const int* in_sizes, int n_in,
                              void* d_out, int out_size, void* d_ws, size_t ws_size,
                              hipStream_t stream) {
    const float* sm    = (const float*)d_in[0];
    const float* emb   = (const float*)d_in[1];
    const float* w_ih  = (const float*)d_in[2];
    const float* w_hh  = (const float*)d_in[3];
    const float* b_ih  = (const float*)d_in[4];
    const float* b_hh  = (const float*)d_in[5];
    const float* w_out = (const float*)d_in[6];
    const float* b_out = (const float*)d_in[7];
    const float* cw    = (const float*)d_in[8];
    const float* cb    = (const float*)d_in[9];
    const float* ew    = (const float*)d_in[10];
    const float* eb    = (const float*)d_in[11];

    float* out0 = (float*)d_out;                   // decoder_output  [512,512]
    float* out1 = out0 + (size_t)Bsz * Vd;         // decoder_hidden  [30,512,1024]
    float* out2 = out1 + (size_t)NSTEP * Bsz * Hd; // decoded_indices [31,512]

    char* wsp = (char*)d_ws;
    float*  f_gi  = (float*)wsp;  wsp += sizeof(float) * Bsz * 3072;
    float*  f_h0  = (float*)wsp;  wsp += sizeof(float) * Bsz * Hd;
    float*  f_log = (float*)wsp;  wsp += sizeof(float) * Bsz * Vd;
    u64*    Ppk0  = (u64*)wsp;    wsp += sizeof(u64) * Bsz;
    u64*    Ppk1  = (u64*)wsp;    wsp += sizeof(u64) * Bsz;
    ushort* ApHi0 = (ushort*)wsp; wsp += sizeof(ushort) * Bsz * Hd;
    ushort* ApLo0 = (ushort*)wsp; wsp += sizeof(ushort) * Bsz * Hd;
    ushort* ApHi1 = (ushort*)wsp; wsp += sizeof(ushort) * Bsz * Hd;
    ushort* ApLo1 = (ushort*)wsp; wsp += sizeof(ushort) * Bsz * Hd;
    ushort* embH  = (ushort*)wsp; wsp += sizeof(ushort) * Vd * Hd;
    ushort* embL  = (ushort*)wsp; wsp += sizeof(ushort) * Vd * Hd;
    ushort* wihH  = (ushort*)wsp; wsp += sizeof(ushort) * 3072 * Hd;
    ushort* wihL  = (ushort*)wsp; wsp += sizeof(ushort) * 3072 * Hd;
    ushort* whhH  = (ushort*)wsp; wsp += sizeof(ushort) * 3072 * Hd;
    ushort* whhL  = (ushort*)wsp; wsp += sizeof(ushort) * 3072 * Hd;
    ushort* woutH = (ushort*)wsp; wsp += sizeof(ushort) * Vd * Hd;
    ushort* woutL = (ushort*)wsp; wsp += sizeof(ushort) * Vd * Hd;
    ushort* cwBH  = (ushort*)wsp; wsp += sizeof(ushort) * 2 * 40 * 64 * 8;
    ushort* cwBL  = (ushort*)wsp; wsp += sizeof(ushort) * 2 * 40 * 64 * 8;

    // one-time setup
    k_packconv<<<160, 256, 0, stream>>>(cw, cwBH, cwBL);
    k_packall<<<(7340032 + 255) / 256, 256, 0, stream>>>(
        w_ih, wihH, wihL, w_hh, whhH, whhL, w_out, woutH, woutL, emb, embH, embL);
    k_convmfma<<<256, 512, 0, stream>>>(sm, cwBH, cwBL, cb, ew, eb,
                                        f_h0, ApHi0, ApLo0);
    k_gi<<<256, 512, 0, stream>>>(embH, embL, wihH, wihL, b_ih, f_gi);
    k_init<<<8, 64, 0, stream>>>(Ppk0, out2);

    ushort* aH[2] = {ApHi0, ApHi1};
    ushort* aL[2] = {ApLo0, ApLo1};
    u64* P[2] = {Ppk0, Ppk1};
    for (int t = 0; t < NSTEP; ++t) {
        int cur = t & 1, nxt = cur ^ 1;
        const float* hOld = (t == 0) ? f_h0 : (out1 + (size_t)(t - 1) * Bsz * Hd);
        k_rnnS<<<512, 256, 0, stream>>>(
            aH[cur], aL[cur], whhH, whhL, b_hh, out1 + (size_t)t * Bsz * Hd,
            f_gi, P[cur], P[nxt],
            (t >= 1) ? (out2 + (size_t)t * Bsz) : nullptr,
            hOld, aH[nxt], aL[nxt]);
        k_lgt<<<256, 256, 0, stream>>>(aH[nxt], aL[nxt], woutH, woutL, b_out,
                                       (t == NSTEP - 1) ? f_log : nullptr,
                                       P[nxt]);
    }
    k_fin<<<Bsz, 64, 0, stream>>>(f_log, P[NSTEP & 1], out0,
                                  out2 + (size_t)NSTEP * Bsz);
}

// Round 17
// 750.285 us; speedup vs baseline: 1.0465x; 1.0465x over previous
//
#include <hip/hip_runtime.h>
#include <hip/hip_bf16.h>
#include <math.h>

#define Bsz 512
#define Hd 1024
#define Vd 512
#define Cc 128
#define Ll 120
#define Kk 10
#define Oo 32
#define NSTEP 30

typedef __attribute__((ext_vector_type(8))) short bf16x8;
typedef __attribute__((ext_vector_type(4))) float f32x4;
typedef unsigned short ushort;
typedef unsigned long long u64;

// raw barrier: drain LDS ops only; global loads stay in flight (counted vmcnt at use)
#define BARLDS() asm volatile("s_waitcnt lgkmcnt(0)\n\ts_barrier" ::: "memory")

static __device__ __forceinline__ float sigm(float x) { return 1.f / (1.f + expf(-x)); }
static __device__ __forceinline__ ushort f2bf(float x) {
    __hip_bfloat16 h = __float2bfloat16(x);
    return *(ushort*)&h;
}
static __device__ __forceinline__ float bf2f(ushort u) {
    __hip_bfloat16 h; *(ushort*)&h = u;
    return __bfloat162float(h);
}
static __device__ __forceinline__ unsigned monofy(float f) {
    unsigned u = __float_as_uint(f);
    return (u & 0x80000000u) ? ~u : (u | 0x80000000u);
}

// ---------- merged pack: wih | whh | wout | emb in one launch ----------
__global__ void k_packall(const float* __restrict__ wih, ushort* __restrict__ wihH, ushort* __restrict__ wihL,
                          const float* __restrict__ whh, ushort* __restrict__ whhH, ushort* __restrict__ whhL,
                          const float* __restrict__ wout, ushort* __restrict__ woutH, ushort* __restrict__ woutL,
                          const float* __restrict__ emb, ushort* __restrict__ embH, ushort* __restrict__ embL) {
    int gidx = blockIdx.x * 256 + threadIdx.x;
    const float* W;
    ushort *hi, *lo;
    int idx;
    if (gidx < 3145728)      { W = wih;  hi = wihH;  lo = wihL;  idx = gidx; }
    else if (gidx < 6291456) { W = whh;  hi = whhH;  lo = whhL;  idx = gidx - 3145728; }
    else if (gidx < 6815744) { W = wout; hi = woutH; lo = woutL; idx = gidx - 6291456; }
    else if (gidx < 7340032) { W = emb;  hi = embH;  lo = embL;  idx = gidx - 6815744; }
    else return;
    int jj = idx & 7, l = (idx >> 3) & 63, c = (idx >> 9) & 31, nf = idx >> 14;
    int n = nf * 16 + (l & 15);
    int k = c * 32 + ((l >> 4) << 3) + jj;
    float v = W[(size_t)n * 1024 + k];
    ushort h = f2bf(v);
    hi[idx] = h;
    lo[idx] = f2bf(v - bf2f(h));
}

// ---------- pack conv_w [O,C,K] into B-frag layout over K'=(kconv,c)=1280 ----------
__global__ void k_packconv(const float* __restrict__ cw, ushort* __restrict__ hi,
                           ushort* __restrict__ lo) {
    int idx = blockIdx.x * 256 + threadIdx.x;
    if (idx >= 2 * 40 * 64 * 8) return;
    int jj = idx & 7, l = (idx >> 3) & 63, ch = (idx >> 9) % 40, nf = idx / (40 * 512);
    int o = nf * 16 + (l & 15);
    int k = ch * 32 + ((l >> 4) << 3) + jj;
    int kc = k >> 7, c = k & 127;
    float v = cw[(o * Cc + c) * Kk + kc];
    ushort h = f2bf(v);
    hi[idx] = h;
    lo[idx] = f2bf(v - bf2f(h));
}

// ---------- conv v3: dual-slab blocks (round-12/14 measured good) ----------
__global__ __launch_bounds__(512) void k_convmfma(const float* __restrict__ sm,
                                                  const ushort* __restrict__ wH,
                                                  const ushort* __restrict__ wL,
                                                  const float* __restrict__ cb,
                                                  const float* __restrict__ ew,
                                                  const float* __restrict__ eb,
                                                  float* __restrict__ h0,
                                                  ushort* __restrict__ ApHi,
                                                  ushort* __restrict__ ApLo) {
    __shared__ ushort hiS[2][137 * 128];
    __shared__ ushort loS[2][137 * 128];
    __shared__ float sred[8][2][2][16];
    __shared__ float ps[2][Oo];
    int b0 = blockIdx.x * 2, tid = threadIdx.x, wid = tid >> 6, l = tid & 63;

    for (int i = tid; i < 3840; i += 512) {
        int s = i >= 1920;
        int local = i - s * 1920;
        int row = local >> 4, col0 = (local & 15) * 8;
        const float* smb = sm + (size_t)(b0 + s) * (Ll * Cc);
        float4 fa = *(const float4*)(smb + row * Cc + col0);
        float4 fb = *(const float4*)(smb + row * Cc + col0 + 4);
        float vv[8] = {fa.x, fa.y, fa.z, fa.w, fb.x, fb.y, fb.z, fb.w};
        ushort h8[8], l8[8];
#pragma unroll
        for (int q = 0; q < 8; ++q) {
            ushort h = f2bf(vv[q]);
            h8[q] = h;
            l8[q] = f2bf(vv[q] - bf2f(h));
        }
        int o = ((row << 8) + (col0 << 1)) ^ ((row & 7) << 4);
        *(bf16x8*)((char*)hiS[s] + o) = *(bf16x8*)h8;
        *(bf16x8*)((char*)loS[s] + o) = *(bf16x8*)l8;
    }
    __syncthreads();

    f32x4 acc[2][2];
#pragma unroll
    for (int s = 0; s < 2; ++s)
#pragma unroll
        for (int j = 0; j < 2; ++j) acc[s][j] = (f32x4)0.f;

    bf16x8 aH0[2], aL0[2], bH0[2], bL0[2];
    bf16x8 aH1[2], aL1[2], bH1[2], bL1[2];

#define CLD(AH, AL, BH, BL, ch)                                                        \
    {                                                                                  \
        int row = wid * 16 + (l & 15) + ((ch) >> 2);                                   \
        int o = ((row << 8) + ((((ch) & 3) * 32 + ((l >> 4) << 3)) << 1))              \
                ^ ((row & 7) << 4);                                                    \
        _Pragma("unroll") for (int s = 0; s < 2; ++s) {                                \
            AH[s] = *(const bf16x8*)((const char*)hiS[s] + o);                         \
            AL[s] = *(const bf16x8*)((const char*)loS[s] + o);                         \
        }                                                                              \
        _Pragma("unroll") for (int nf = 0; nf < 2; ++nf) {                             \
            int boff = ((nf * 40 + (ch)) * 64 + l) * 8;                                \
            BH[nf] = *(const bf16x8*)(wH + boff);                                      \
            BL[nf] = *(const bf16x8*)(wL + boff);                                      \
        }                                                                              \
    }
#define CST(AH, AL, BH, BL)                                                            \
    {                                                                                  \
        _Pragma("unroll") for (int s = 0; s < 2; ++s)                                  \
            _Pragma("unroll") for (int nf = 0; nf < 2; ++nf) {                         \
                acc[s][nf] = __builtin_amdgcn_mfma_f32_16x16x32_bf16(AH[s], BH[nf], acc[s][nf], 0, 0, 0); \
                acc[s][nf] = __builtin_amdgcn_mfma_f32_16x16x32_bf16(AH[s], BL[nf], acc[s][nf], 0, 0, 0); \
                acc[s][nf] = __builtin_amdgcn_mfma_f32_16x16x32_bf16(AL[s], BH[nf], acc[s][nf], 0, 0, 0); \
            }                                                                          \
    }

    CLD(aH0, aL0, bH0, bL0, 0)
#pragma unroll
    for (int ch = 0; ch < 40; ch += 2) {
        CLD(aH1, aL1, bH1, bL1, ch + 1)
        CST(aH0, aL0, bH0, bL0)
        if (ch + 2 < 40) CLD(aH0, aL0, bH0, bL0, ch + 2)
        CST(aH1, aL1, bH1, bL1)
    }
#undef CLD
#undef CST

    float mx[2][2] = {{-1e38f, -1e38f}, {-1e38f, -1e38f}};
    {
        int tb = wid * 16 + ((l >> 4) << 2);
#pragma unroll
        for (int q = 0; q < 4; ++q) {
            if (tb + q <= 110) {
#pragma unroll
                for (int s = 0; s < 2; ++s) {
                    mx[s][0] = fmaxf(mx[s][0], acc[s][0][q]);
                    mx[s][1] = fmaxf(mx[s][1], acc[s][1][q]);
                }
            }
        }
    }
#pragma unroll
    for (int sh = 16; sh < 64; sh <<= 1) {
#pragma unroll
        for (int s = 0; s < 2; ++s) {
            mx[s][0] = fmaxf(mx[s][0], __shfl_xor(mx[s][0], sh));
            mx[s][1] = fmaxf(mx[s][1], __shfl_xor(mx[s][1], sh));
        }
    }
    if (l < 16) {
#pragma unroll
        for (int s = 0; s < 2; ++s) {
            sred[wid][s][0][l] = mx[s][0];
            sred[wid][s][1][l] = mx[s][1];
        }
    }
    __syncthreads();
    if (tid < 64) {
        int s = tid >> 5, o = tid & 31;
        float m = sred[0][s][o >> 4][o & 15];
#pragma unroll
        for (int w = 1; w < 8; ++w) m = fmaxf(m, sred[w][s][o >> 4][o & 15]);
        ps[s][o] = fmaxf(m + cb[o], 0.f);
    }
    __syncthreads();
    for (int j = tid; j < Hd; j += 512) {
        const float4* e4 = (const float4*)(ew + (size_t)j * Oo);
        float4 w0 = e4[0], w1 = e4[1], w2 = e4[2], w3 = e4[3];
        float4 w4 = e4[4], w5 = e4[5], w6 = e4[6], w7 = e4[7];
        float ebj = eb[j];
        int c = j >> 5, sub = (j >> 3) & 3, jj = j & 7;
#pragma unroll
        for (int s = 0; s < 2; ++s) {
            int b = b0 + s;
            const float* p = ps[s];
            float a = ebj;
            a += p[0] * w0.x + p[1] * w0.y + p[2] * w0.z + p[3] * w0.w;
            a += p[4] * w1.x + p[5] * w1.y + p[6] * w1.z + p[7] * w1.w;
            a += p[8] * w2.x + p[9] * w2.y + p[10] * w2.z + p[11] * w2.w;
            a += p[12] * w3.x + p[13] * w3.y + p[14] * w3.z + p[15] * w3.w;
            a += p[16] * w4.x + p[17] * w4.y + p[18] * w4.z + p[19] * w4.w;
            a += p[20] * w5.x + p[21] * w5.y + p[22] * w5.z + p[23] * w5.w;
            a += p[24] * w6.x + p[25] * w6.y + p[26] * w6.z + p[27] * w6.w;
            a += p[28] * w7.x + p[29] * w7.y + p[30] * w7.z + p[31] * w7.w;
            a = fmaxf(a, 0.f);
            h0[(size_t)b * Hd + j] = a;
            ushort hb = f2bf(a);
            ushort lb = f2bf(a - bf2f(hb));
            int amf = b >> 4;
            int lane_r = (b & 15) + (sub << 4);
            int flat = ((amf * 32 + c) * 64 + lane_r) * 8 + jj;
            ApHi[flat] = hb;
            ApLo[flat] = lb;
        }
    }
}

// ---------- gi table (setup): r6-verified 8-wave GEMM, plain store epilogue ----------
__global__ __launch_bounds__(512, 2) void k_gi(const ushort* __restrict__ Ah,
                                               const ushort* __restrict__ Al,
                                               const ushort* __restrict__ Bh,
                                               const ushort* __restrict__ Bl,
                                               const float* __restrict__ bias,
                                               float* __restrict__ outF) {
    __shared__ ushort Bs[2][48][512];
    int id = blockIdx.x;
    int xcd = id & 7, r = id >> 3;
    int jt = xcd * 4 + (r & 3);
    int mt = r >> 2;
    int tid = threadIdx.x, wid = tid >> 6, l = tid & 63;
    int wm = wid >> 1, wj = wid & 1;
    int mf = mt * 4 + wm;
    int jf = jt * 2 + wj;
    int jcol = jf * 16 + (l & 15);

    f32x4 acc[3];
#pragma unroll
    for (int g = 0; g < 3; ++g) acc[g] = (f32x4)0.f;

    bf16x8 stg[6], aH0[4], aL0[4], aH1[4], aL1[4];

#define STG_LD(it)                                                                     \
    {                                                                                  \
        _Pragma("unroll") for (int k = 0; k < 6; ++k) {                                \
            int u = wid + 8 * k;                                                       \
            int hl = u & 1, wjb = (u >> 1) & 1, g = (u >> 2) % 3, cu = u / 12;         \
            const ushort* sp = hl ? Bl : Bh;                                           \
            stg[k] = *(const bf16x8*)(sp +                                             \
                (size_t)(((g * 64 + jt * 2 + wjb) * 32 + (it) * 4 + cu) * 64 + l) * 8);\
        }                                                                              \
    }
#define STG_WR(buf)                                                                    \
    {                                                                                  \
        _Pragma("unroll") for (int k = 0; k < 6; ++k)                                  \
            *(bf16x8*)&Bs[buf][wid + 8 * k][l * 8] = stg[k];                           \
    }
#define A_LD(DH, DL, it)                                                               \
    {                                                                                  \
        _Pragma("unroll") for (int cc = 0; cc < 4; ++cc) {                             \
            DH[cc] = *(const bf16x8*)(Ah + (size_t)((mf * 32 + (it) * 4 + cc) * 64 + l) * 8); \
            DL[cc] = *(const bf16x8*)(Al + (size_t)((mf * 32 + (it) * 4 + cc) * 64 + l) * 8); \
        }                                                                              \
    }
#define CMP(buf, AH, AL)                                                               \
    {                                                                                  \
        _Pragma("unroll") for (int cc = 0; cc < 4; ++cc)                               \
            _Pragma("unroll") for (int g = 0; g < 3; ++g) {                            \
                bf16x8 bhh = *(const bf16x8*)&Bs[buf][cc * 12 + g * 4 + wj * 2 + 0][l * 8]; \
                bf16x8 bll = *(const bf16x8*)&Bs[buf][cc * 12 + g * 4 + wj * 2 + 1][l * 8]; \
                acc[g] = __builtin_amdgcn_mfma_f32_16x16x32_bf16(AH[cc], bhh, acc[g], 0, 0, 0); \
                acc[g] = __builtin_amdgcn_mfma_f32_16x16x32_bf16(AH[cc], bll, acc[g], 0, 0, 0); \
                acc[g] = __builtin_amdgcn_mfma_f32_16x16x32_bf16(AL[cc], bhh, acc[g], 0, 0, 0); \
            }                                                                          \
    }

    STG_LD(0)
    STG_WR(0)
    STG_LD(1)
    A_LD(aH0, aL0, 0)
    BARLDS();
#pragma unroll
    for (int it = 0; it < 8; ++it) {
        int buf = it & 1;
        if (it < 7) STG_WR(buf ^ 1)
        if (it < 6) STG_LD(it + 2)
        if (it & 1) {
            if (it < 7) A_LD(aH0, aL0, it + 1)
            CMP(buf, aH1, aL1)
        } else {
            if (it < 7) A_LD(aH1, aL1, it + 1)
            CMP(buf, aH0, aL0)
        }
        BARLDS();
    }
#undef STG_LD
#undef STG_WR
#undef A_LD
#undef CMP

#pragma unroll
    for (int q = 0; q < 4; ++q) {
        int b = mf * 16 + ((l >> 4) << 2) + q;
#pragma unroll
        for (int g = 0; g < 3; ++g)
            outF[(size_t)b * 3072 + g * 1024 + jcol] = acc[g][q] + bias[g * 1024 + jcol];
    }
}

// ---------- recurrent GEMM v4: 512 blocks x 4 waves, 24 KB dbuf -> 2+ blocks/CU ----------
// grid 512 = 8 mt x 64 jf (jf XCD-pinned); block: M=64 rows (4 mf, 1/wave) x 16 j x 3 g.
// r9's refcheck-passed staging layout + r6's 1-ahead A prefetch + counted-vmcnt barriers.
__global__ __launch_bounds__(256, 2) void k_rnnS(const ushort* __restrict__ Ah,
                                                 const ushort* __restrict__ Al,
                                                 const ushort* __restrict__ Bh,
                                                 const ushort* __restrict__ Bl,
                                                 const float* __restrict__ bias,
                                                 float* __restrict__ outF,
                                                 const float* __restrict__ gi_all,
                                                 const u64* __restrict__ pkRd,
                                                 u64* __restrict__ pkWr,
                                                 float* __restrict__ outIdxRow,
                                                 const float* __restrict__ hOld,
                                                 ushort* __restrict__ ApHi,
                                                 ushort* __restrict__ ApLo) {
    __shared__ ushort Bs[2][12][512];   // 24 KB dbuf
    int id = blockIdx.x;
    int xcd = id & 7, r = id >> 3;      // r 0..63
    int jf = xcd * 8 + (r & 7);         // 0..63 (8 jf per XCD -> panel L2-resident)
    int mt = r >> 3;                    // 0..7
    int tid = threadIdx.x, wm = tid >> 6, l = tid & 63;
    int mf = mt * 4 + wm;               // 0..31
    int jcol = jf * 16 + (l & 15);

    f32x4 acc[3];
#pragma unroll
    for (int g = 0; g < 3; ++g) acc[g] = (f32x4)0.f;

    bf16x8 stg[3], aH0[2], aL0[2], aH1[2], aL1[2];

#define SSTG_LD(it)                                                                    \
    {                                                                                  \
        _Pragma("unroll") for (int k = 0; k < 3; ++k) {                                \
            int s = tid + 256 * k;                                                     \
            int il = s & 63, u = s >> 6;                                               \
            int hl = u & 1, g = (u >> 1) % 3, cu = u / 6;                              \
            const ushort* sp = hl ? Bl : Bh;                                           \
            stg[k] = *(const bf16x8*)(sp +                                             \
                (size_t)(((g * 64 + jf) * 32 + (it) * 2 + cu) * 64 + il) * 8);         \
        }                                                                              \
    }
#define SSTG_WR(buf)                                                                   \
    {                                                                                  \
        _Pragma("unroll") for (int k = 0; k < 3; ++k) {                                \
            int s = tid + 256 * k;                                                     \
            int il = s & 63, u = s >> 6;                                               \
            *(bf16x8*)&Bs[buf][u][il * 8] = stg[k];                                    \
        }                                                                              \
    }
#define SA_LD(DH, DL, it)                                                              \
    {                                                                                  \
        _Pragma("unroll") for (int cc = 0; cc < 2; ++cc) {                             \
            size_t off = (size_t)((mf * 32 + (it) * 2 + cc) * 64 + l) * 8;             \
            DH[cc] = *(const bf16x8*)(Ah + off);                                       \
            DL[cc] = *(const bf16x8*)(Al + off);                                       \
        }                                                                              \
    }
#define SCMP(buf, AH, AL)                                                              \
    {                                                                                  \
        _Pragma("unroll") for (int cc = 0; cc < 2; ++cc)                               \
            _Pragma("unroll") for (int g = 0; g < 3; ++g) {                            \
                bf16x8 bhh = *(const bf16x8*)&Bs[buf][cc * 6 + g * 2 + 0][l * 8];      \
                bf16x8 bll = *(const bf16x8*)&Bs[buf][cc * 6 + g * 2 + 1][l * 8];      \
                acc[g] = __builtin_amdgcn_mfma_f32_16x16x32_bf16(AH[cc], bhh, acc[g], 0, 0, 0); \
                acc[g] = __builtin_amdgcn_mfma_f32_16x16x32_bf16(AH[cc], bll, acc[g], 0, 0, 0); \
                acc[g] = __builtin_amdgcn_mfma_f32_16x16x32_bf16(AL[cc], bhh, acc[g], 0, 0, 0); \
            }                                                                          \
    }

    SSTG_LD(0)
    SSTG_WR(0)
    SSTG_LD(1)
    SA_LD(aH0, aL0, 0)

    // epilogue operand gather issued early (overlaps the K-loop)
    float giR[4][3], hR[4];
    int bR[4], tkR[4];
#pragma unroll
    for (int q = 0; q < 4; ++q) {
        bR[q] = mf * 16 + ((l >> 4) << 2) + q;
        u64 pk = pkRd[bR[q]];
        tkR[q] = 511 - (int)(unsigned)(pk & 0xFFFFFFFFu);
        const float* gi = gi_all + (size_t)tkR[q] * 3072;
        giR[q][0] = gi[jcol];
        giR[q][1] = gi[1024 + jcol];
        giR[q][2] = gi[2048 + jcol];
        hR[q] = hOld[(size_t)bR[q] * 1024 + jcol];
    }
    if (jf == 0 && (l & 15) == 0) {
#pragma unroll
        for (int q = 0; q < 4; ++q) {
            pkWr[bR[q]] = 0ULL;
            if (outIdxRow) outIdxRow[bR[q]] = (float)tkR[q];
        }
    }

    BARLDS();
#pragma unroll
    for (int it = 0; it < 16; ++it) {
        int buf = it & 1;
        if (it < 15) SSTG_WR(buf ^ 1)
        if (it < 14) SSTG_LD(it + 2)
        if (it & 1) {
            if (it < 15) SA_LD(aH0, aL0, it + 1)
            SCMP(buf, aH1, aL1)
        } else {
            if (it < 15) SA_LD(aH1, aL1, it + 1)
            SCMP(buf, aH0, aL0)
        }
        BARLDS();
    }
#undef SSTG_LD
#undef SSTG_WR
#undef SA_LD
#undef SCMP

    {
        float bj0 = bias[jcol], bj1 = bias[1024 + jcol], bj2 = bias[2048 + jcol];
        int c = jcol >> 5, sub = (jcol >> 3) & 3, jj = jcol & 7;
#pragma unroll
        for (int q = 0; q < 4; ++q) {
            int b = bR[q];
            float rr = sigm(giR[q][0] + acc[0][q] + bj0);
            float zz = sigm(giR[q][1] + acc[1][q] + bj1);
            float nn = tanhf(giR[q][2] + rr * (acc[2][q] + bj2));
            float hv = (1.f - zz) * nn + zz * hR[q];
            outF[(size_t)b * 1024 + jcol] = hv;
            ushort hb = f2bf(hv);
            ushort lb = f2bf(hv - bf2f(hb));
            int lane_r = (b & 15) + (sub << 4);
            int flat = (((b >> 4) * 32 + c) * 64 + lane_r) * 8 + jj;
            ApHi[flat] = hb;
            ApLo[flat] = lb;
        }
    }
}

// ---------- logits GEMM: B vf-panel LDS-staged + A register prefetch + fused argmax ----------
__global__ __launch_bounds__(256) void k_lgt(const ushort* __restrict__ Ah,
                                             const ushort* __restrict__ Al,
                                             const ushort* __restrict__ Bh,
                                             const ushort* __restrict__ Bl,
                                             const float* __restrict__ bias,
                                             float* __restrict__ outF,
                                             u64* __restrict__ pkOut) {
    __shared__ ushort Bs[2][8][512];    // 16 KB
    int id = blockIdx.x;
    int xcd = id & 7, r = id >> 3;
    int vf = xcd * 4 + (r & 3);
    int mg = r >> 2;
    int tid = threadIdx.x, w = tid >> 6, l = tid & 63;
    int mf = mg * 4 + w;

    f32x4 acc = (f32x4)0.f;
    bf16x8 stg[2];
    bf16x8 a0h[4], a0l[4], a1h[4], a1l[4];

#define LSTG_LD(it)                                                                    \
    {                                                                                  \
        _Pragma("unroll") for (int k = 0; k < 2; ++k) {                                \
            int s = tid + 256 * k;                                                     \
            int il = s & 63, u = s >> 6;                                               \
            int hl = u & 1, cu = u >> 1;                                               \
            const ushort* sp = hl ? Bl : Bh;                                           \
            stg[k] = *(const bf16x8*)(sp +                                             \
                (size_t)((vf * 32 + (it) * 4 + cu) * 64 + il) * 8);                    \
        }                                                                              \
    }
#define LSTG_WR(buf)                                                                   \
    {                                                                                  \
        _Pragma("unroll") for (int k = 0; k < 2; ++k) {                                \
            int s = tid + 256 * k;                                                     \
            int il = s & 63, u = s >> 6;                                               \
            *(bf16x8*)&Bs[buf][u][il * 8] = stg[k];                                    \
        }                                                                              \
    }
#define LA_LD(DH, DL, it)                                                              \
    {                                                                                  \
        _Pragma("unroll") for (int cu = 0; cu < 4; ++cu) {                             \
            size_t aoff = (size_t)((mf * 32 + (it) * 4 + cu) * 64 + l) * 8;            \
            DH[cu] = *(const bf16x8*)(Ah + aoff);                                      \
            DL[cu] = *(const bf16x8*)(Al + aoff);                                      \
        }                                                                              \
    }
#define LCMP(buf, AH, AL)                                                              \
    {                                                                                  \
        _Pragma("unroll") for (int cu = 0; cu < 4; ++cu) {                             \
            bf16x8 bh = *(const bf16x8*)&Bs[buf][cu * 2 + 0][l * 8];                   \
            bf16x8 bl = *(const bf16x8*)&Bs[buf][cu * 2 + 1][l * 8];                   \
            acc = __builtin_amdgcn_mfma_f32_16x16x32_bf16(AH[cu], bh, acc, 0, 0, 0);   \
            acc = __builtin_amdgcn_mfma_f32_16x16x32_bf16(AH[cu], bl, acc, 0, 0, 0);   \
            acc = __builtin_amdgcn_mfma_f32_16x16x32_bf16(AL[cu], bh, acc, 0, 0, 0);   \
        }                                                                              \
    }

    LSTG_LD(0)
    LSTG_WR(0)
    LSTG_LD(1)
    LA_LD(a0h, a0l, 0)
    BARLDS();
#pragma unroll
    for (int it = 0; it < 8; ++it) {
        int buf = it & 1;
        if (it < 7) LSTG_WR(buf ^ 1)
        if (it < 6) LSTG_LD(it + 2)
        if (it & 1) {
            if (it < 7) LA_LD(a0h, a0l, it + 1)
            LCMP(buf, a1h, a1l)
        } else {
            if (it < 7) LA_LD(a1h, a1l, it + 1)
            LCMP(buf, a0h, a0l)
        }
        BARLDS();
    }
#undef LSTG_LD
#undef LSTG_WR
#undef LA_LD
#undef LCMP

    int v = vf * 16 + (l & 15);
    float bv = bias[v];
    float lg[4];
    unsigned vmq[4];
#pragma unroll
    for (int q = 0; q < 4; ++q) {
        int b = mf * 16 + ((l >> 4) << 2) + q;
        lg[q] = acc[q] + bv;
        if (outF) outF[(size_t)b * Vd + v] = lg[q];
        vmq[q] = 511u - (unsigned)v;
    }
#pragma unroll
    for (int off = 1; off < 16; off <<= 1) {
#pragma unroll
        for (int q = 0; q < 4; ++q) {
            float og = __shfl_xor(lg[q], off);
            unsigned ov = __shfl_xor(vmq[q], off);
            if (og > lg[q] || (og == lg[q] && ov > vmq[q])) { lg[q] = og; vmq[q] = ov; }
        }
    }
    if ((l & 15) == 0) {
#pragma unroll
        for (int q = 0; q < 4; ++q) {
            int b = mf * 16 + ((l >> 4) << 2) + q;
            u64 pk = ((u64)monofy(lg[q]) << 32) | (u64)vmq[q];
            atomicMax(&pkOut[b], pk);
        }
    }
}

// ---------- final: log_softmax of last logits + decoded_indices row 30 ----------
__global__ __launch_bounds__(64) void k_fin(const float* __restrict__ logits,
                                            const u64* __restrict__ pk,
                                            float* __restrict__ out_lsm,
                                            float* __restrict__ outIdxRow) {
    int b = blockIdx.x, l = threadIdx.x;
    const float* row = logits + (size_t)b * Vd;
    float bv = -3.4e38f;
#pragma unroll
    for (int s = 0; s < 8; ++s) bv = fmaxf(bv, row[s * 64 + l]);
#pragma unroll
    for (int off = 1; off < 64; off <<= 1) bv = fmaxf(bv, __shfl_xor(bv, off));
    float sum = 0.f;
#pragma unroll
    for (int s = 0; s < 8; ++s) sum += expf(row[s * 64 + l] - bv);
#pragma unroll
    for (int off = 1; off < 64; off <<= 1) sum += __shfl_xor(sum, off);
    float lse = logf(sum) + bv;
#pragma unroll
    for (int s = 0; s < 8; ++s) {
        int v = s * 64 + l;
        out_lsm[(size_t)b * Vd + v] = row[v] - lse;
    }
    if (l == 0)
        outIdxRow[b] = (float)(511 - (int)(unsigned)(pk[b] & 0xFFFFFFFFu));
}

__global__ void k_init(u64* __restrict__ P0, float* __restrict__ out_idx0) {
    int i = blockIdx.x * 64 + threadIdx.x;
    if (i < Bsz) {
        P0[i] = (1ULL << 32) | 511ULL;   // decodes to token 0 (SOS)
        out_idx0[i] = 0.f;
    }
}

extern "C" void kernel_launch(void* const* d_in, const int* in_sizes, int n_in,
                              void* d_out, int out_size, void* d_ws, size_t ws_size,
                              hipStream_t stream) {
    const float* sm    = (const float*)d_in[0];
    const float* emb   = (const float*)d_in[1];
    const float* w_ih  = (const float*)d_in[2];
    const float* w_hh  = (const float*)d_in[3];
    const float* b_ih  = (const float*)d_in[4];
    const float* b_hh  = (const float*)d_in[5];
    const float* w_out = (const float*)d_in[6];
    const float* b_out = (const float*)d_in[7];
    const float* cw    = (const float*)d_in[8];
    const float* cb    = (const float*)d_in[9];
    const float* ew    = (const float*)d_in[10];
    const float* eb    = (const float*)d_in[11];

    float* out0 = (float*)d_out;                   // decoder_output  [512,512]
    float* out1 = out0 + (size_t)Bsz * Vd;         // decoder_hidden  [30,512,1024]
    float* out2 = out1 + (size_t)NSTEP * Bsz * Hd; // decoded_indices [31,512]

    char* wsp = (char*)d_ws;
    float*  f_gi  = (float*)wsp;  wsp += sizeof(float) * Bsz * 3072;
    float*  f_h0  = (float*)wsp;  wsp += sizeof(float) * Bsz * Hd;
    float*  f_log = (float*)wsp;  wsp += sizeof(float) * Bsz * Vd;
    u64*    Ppk0  = (u64*)wsp;    wsp += sizeof(u64) * Bsz;
    u64*    Ppk1  = (u64*)wsp;    wsp += sizeof(u64) * Bsz;
    ushort* ApHi0 = (ushort*)wsp; wsp += sizeof(ushort) * Bsz * Hd;
    ushort* ApLo0 = (ushort*)wsp; wsp += sizeof(ushort) * Bsz * Hd;
    ushort* ApHi1 = (ushort*)wsp; wsp += sizeof(ushort) * Bsz * Hd;
    ushort* ApLo1 = (ushort*)wsp; wsp += sizeof(ushort) * Bsz * Hd;
    ushort* embH  = (ushort*)wsp; wsp += sizeof(ushort) * Vd * Hd;
    ushort* embL  = (ushort*)wsp; wsp += sizeof(ushort) * Vd * Hd;
    ushort* wihH  = (ushort*)wsp; wsp += sizeof(ushort) * 3072 * Hd;
    ushort* wihL  = (ushort*)wsp; wsp += sizeof(ushort) * 3072 * Hd;
    ushort* whhH  = (ushort*)wsp; wsp += sizeof(ushort) * 3072 * Hd;
    ushort* whhL  = (ushort*)wsp; wsp += sizeof(ushort) * 3072 * Hd;
    ushort* woutH = (ushort*)wsp; wsp += sizeof(ushort) * Vd * Hd;
    ushort* woutL = (ushort*)wsp; wsp += sizeof(ushort) * Vd * Hd;
    ushort* cwBH  = (ushort*)wsp; wsp += sizeof(ushort) * 2 * 40 * 64 * 8;
    ushort* cwBL  = (ushort*)wsp; wsp += sizeof(ushort) * 2 * 40 * 64 * 8;

    // one-time setup
    k_packconv<<<160, 256, 0, stream>>>(cw, cwBH, cwBL);
    k_packall<<<(7340032 + 255) / 256, 256, 0, stream>>>(
        w_ih, wihH, wihL, w_hh, whhH, whhL, w_out, woutH, woutL, emb, embH, embL);
    k_convmfma<<<256, 512, 0, stream>>>(sm, cwBH, cwBL, cb, ew, eb,
                                        f_h0, ApHi0, ApLo0);
    k_gi<<<256, 512, 0, stream>>>(embH, embL, wihH, wihL, b_ih, f_gi);
    k_init<<<8, 64, 0, stream>>>(Ppk0, out2);

    ushort* aH[2] = {ApHi0, ApHi1};
    ushort* aL[2] = {ApLo0, ApLo1};
    u64* P[2] = {Ppk0, Ppk1};
    for (int t = 0; t < NSTEP; ++t) {
        int cur = t & 1, nxt = cur ^ 1;
        const float* hOld = (t == 0) ? f_h0 : (out1 + (size_t)(t - 1) * Bsz * Hd);
        k_rnnS<<<512, 256, 0, stream>>>(
            aH[cur], aL[cur], whhH, whhL, b_hh, out1 + (size_t)t * Bsz * Hd,
            f_gi, P[cur], P[nxt],
            (t >= 1) ? (out2 + (size_t)t * Bsz) : nullptr,
            hOld, aH[nxt], aL[nxt]);
        k_lgt<<<256, 256, 0, stream>>>(aH[nxt], aL[nxt], woutH, woutL, b_out,
                                       (t == NSTEP - 1) ? f_log : nullptr,
                                       P[nxt]);
    }
    k_fin<<<Bsz, 64, 0, stream>>>(f_log, P[NSTEP & 1], out0,
                                  out2 + (size_t)NSTEP * Bsz);
}